// Round 1
// baseline (37800.641 us; speedup 1.0000x reference)
//
#include <hip/hip_runtime.h>
#include <math.h>

#define NB 256
#define NL 200
#define ND 512

// ---- workspace layout (float offsets) ----
#define SSEQ_OFF 0ul                      // [200][256][512] GRU output sequence (time-major)
#define ATT_OFF  26214400ul               // [256][200] attention weights
#define VT_OFF   (ATT_OFF + 51200ul)      // [256][512] vt = w @ target
#define HBUF_OFF (VT_OFF + 131072ul)      // [2][256][512] h ping-pong
#define HR_OFF   (HBUF_OFF + 262144ul)    // [256][512] r*h for AUGRU phase 2
#define BAR_OFF  (HR_OFF + 131072ul)      // 128 ULL barrier counters (256 floats)

__device__ __forceinline__ float dot4(const float4 a, const float4 b) {
  return a.x * b.x + a.y * b.y + a.z * b.z + a.w * b.w;
}
__device__ __forceinline__ float sigmoidf_(float x) { return 1.0f / (1.0f + expf(-x)); }

// ---- grid barrier: monotonic counter per group, agent-scope ----
__device__ __forceinline__ void bar_arrive(unsigned long long* c) {
  __syncthreads();  // all block writes program-ordered before thread0's release
  if (threadIdx.x == 0) {
    __hip_atomic_fetch_add(c, 1ull, __ATOMIC_RELEASE, __HIP_MEMORY_SCOPE_AGENT);
  }
}
__device__ __forceinline__ void bar_wait(const unsigned long long* c, unsigned long long tgt) {
  if (threadIdx.x == 0) {
    int guard = 0;
    while (__hip_atomic_load(c, __ATOMIC_ACQUIRE, __HIP_MEMORY_SCOPE_AGENT) < tgt) {
      __builtin_amdgcn_s_sleep(1);
      if (++guard > (1 << 22)) break;  // safety: terminate instead of hanging the bench
    }
  }
  __syncthreads();
}

// ---- init: zero h0 and barrier counters (must re-run every call: graph replays) ----
__global__ void init_kernel(float* __restrict__ ws) {
  const int i = blockIdx.x * 256 + threadIdx.x;
  float* const hb = ws + HBUF_OFF;
  for (int j = i; j < 131072; j += 64 * 256) hb[j] = 0.0f;
  if (blockIdx.x == 0 && threadIdx.x < 128) {
    ((unsigned long long*)(ws + BAR_OFF))[threadIdx.x] = 0ull;
  }
}

// ---- vt[b,d] = sum_e w[d,e] * target[b,e] ----
__global__ __launch_bounds__(256) void vt_kernel(const float* __restrict__ w,
                                                 const float* __restrict__ tgt,
                                                 float* __restrict__ ws) {
  __shared__ float t_s[512];
  const int b = blockIdx.x, tid = threadIdx.x;
  for (int i = tid; i < 512; i += 256) t_s[i] = tgt[(size_t)b * 512 + i];
  __syncthreads();
  const int wv = tid >> 6, lane = tid & 63;
  for (int d = wv; d < 512; d += 4) {
    const float* const wr = w + (size_t)d * 512;
    const float4 a  = *(const float4*)(wr + lane * 8);
    const float4 a2 = *(const float4*)(wr + lane * 8 + 4);
    float s = a.x * t_s[lane * 8 + 0] + a.y * t_s[lane * 8 + 1] +
              a.z * t_s[lane * 8 + 2] + a.w * t_s[lane * 8 + 3] +
              a2.x * t_s[lane * 8 + 4] + a2.y * t_s[lane * 8 + 5] +
              a2.z * t_s[lane * 8 + 6] + a2.w * t_s[lane * 8 + 7];
    for (int off = 32; off > 0; off >>= 1) s += __shfl_xor(s, off);
    if (lane == 0) ws[VT_OFF + (size_t)b * 512 + d] = s;
  }
}

// ---- persistent GRU: 256 blocks = 2 batch-halves x 128 col-groups, 200 steps ----
__global__ __launch_bounds__(256) void gru_kernel(const float* __restrict__ session,
                                                  const float* __restrict__ wih,
                                                  const float* __restrict__ whh,
                                                  const float* __restrict__ bih,
                                                  const float* __restrict__ bhh,
                                                  float* __restrict__ ws) {
  __shared__ float wih_s[12 * 512];   // 12 preact rows (3 gates x 4 cols), K=512
  __shared__ float whh_s[12 * 512];
  __shared__ float xp_s[12 * 128];
  __shared__ float hp_s[12 * 128];
  __shared__ float bih_s[12], bhh_s[12];

  const int bg = blockIdx.x >> 7;   // batch half 0/1
  const int ng = blockIdx.x & 127;  // col group
  const int b0 = bg << 7;
  const int c0 = ng << 2;           // 4 h-cols per block
  const int tid = threadIdx.x;

  // LDS slot cc in [0,12): gate g = cc>>2, col q = cc&3 -> global row g*512 + c0 + q
  for (int i = tid; i < 12 * 512; i += 256) {
    const int cc = i >> 9, kk = i & 511;
    const int grow = ((cc >> 2) << 9) + c0 + (cc & 3);
    wih_s[i] = wih[(size_t)grow * 512 + kk];
    whh_s[i] = whh[(size_t)grow * 512 + kk];
  }
  if (tid < 12) {
    const int grow = ((tid >> 2) << 9) + c0 + (tid & 3);
    bih_s[tid] = bih[grow];
    bhh_s[tid] = bhh[grow];
  }
  __syncthreads();

  float* const hbuf = ws + HBUF_OFF;
  float* const sseq = ws + SSEQ_OFF;
  unsigned long long* const bar = (unsigned long long*)(ws + BAR_OFF);
  unsigned long long* const cg = bar + (bg << 4);

  const int bb = tid & 63;   // 2 rows: bb, bb+64
  const int cq = tid >> 6;   // 3 LDS cols: cq*3 .. cq*3+2
  const int rA = b0 + bb, rB = b0 + bb + 64;
  const float* const w0x = wih_s + (cq * 3 + 0) * 512;
  const float* const w1x = wih_s + (cq * 3 + 1) * 512;
  const float* const w2x = wih_s + (cq * 3 + 2) * 512;
  const float* const w0h = whh_s + (cq * 3 + 0) * 512;
  const float* const w1h = whh_s + (cq * 3 + 1) * 512;
  const float* const w2h = whh_s + (cq * 3 + 2) * 512;
  const float* const xAb = session + (size_t)rA * (NL * ND);
  const float* const xBb = session + (size_t)rB * (NL * ND);

  for (int t = 0; t < NL; ++t) {
    // x-projection dots: independent of h -> run before the barrier wait
    const float* const xA = xAb + t * ND;
    const float* const xB = xBb + t * ND;
    float a0 = 0, a1 = 0, a2 = 0, e0 = 0, e1 = 0, e2 = 0;
#pragma unroll 4
    for (int k = 0; k < 512; k += 4) {
      const float4 va = *(const float4*)(xA + k);
      const float4 vb = *(const float4*)(xB + k);
      const float4 u0 = *(const float4*)(w0x + k);
      const float4 u1 = *(const float4*)(w1x + k);
      const float4 u2 = *(const float4*)(w2x + k);
      a0 += dot4(va, u0); a1 += dot4(va, u1); a2 += dot4(va, u2);
      e0 += dot4(vb, u0); e1 += dot4(vb, u1); e2 += dot4(vb, u2);
    }
    if (t > 0) bar_wait(cg, 128ull * (unsigned long long)t);
    const float* const hbase = hbuf + (size_t)(t & 1) * 131072;
    const float* const hA = hbase + (size_t)rA * 512;
    const float* const hB = hbase + (size_t)rB * 512;
    float h0 = 0, h1 = 0, h2 = 0, g0 = 0, g1 = 0, g2 = 0;
#pragma unroll 4
    for (int k = 0; k < 512; k += 4) {
      const float4 va = *(const float4*)(hA + k);
      const float4 vb = *(const float4*)(hB + k);
      const float4 u0 = *(const float4*)(w0h + k);
      const float4 u1 = *(const float4*)(w1h + k);
      const float4 u2 = *(const float4*)(w2h + k);
      h0 += dot4(va, u0); h1 += dot4(va, u1); h2 += dot4(va, u2);
      g0 += dot4(vb, u0); g1 += dot4(vb, u1); g2 += dot4(vb, u2);
    }
    const int cb = cq * 3;
    xp_s[(cb + 0) * 128 + bb] = a0;
    xp_s[(cb + 1) * 128 + bb] = a1;
    xp_s[(cb + 2) * 128 + bb] = a2;
    xp_s[(cb + 0) * 128 + bb + 64] = e0;
    xp_s[(cb + 1) * 128 + bb + 64] = e1;
    xp_s[(cb + 2) * 128 + bb + 64] = e2;
    hp_s[(cb + 0) * 128 + bb] = h0;
    hp_s[(cb + 1) * 128 + bb] = h1;
    hp_s[(cb + 2) * 128 + bb] = h2;
    hp_s[(cb + 0) * 128 + bb + 64] = g0;
    hp_s[(cb + 1) * 128 + bb + 64] = g1;
    hp_s[(cb + 2) * 128 + bb + 64] = g2;
    __syncthreads();

    float* const hout = hbuf + (size_t)((t + 1) & 1) * 131072;
#pragma unroll
    for (int rep = 0; rep < 2; ++rep) {
      const int idx = tid + rep * 256;  // 0..511
      const int rb = idx >> 2, q = idx & 3;
      const int b = b0 + rb;
      const float xr = xp_s[(0 + q) * 128 + rb], hr = hp_s[(0 + q) * 128 + rb];
      const float xz = xp_s[(4 + q) * 128 + rb], hz = hp_s[(4 + q) * 128 + rb];
      const float xn = xp_s[(8 + q) * 128 + rb], hn = hp_s[(8 + q) * 128 + rb];
      const float r = sigmoidf_(xr + bih_s[0 + q] + hr + bhh_s[0 + q]);
      const float z = sigmoidf_(xz + bih_s[4 + q] + hz + bhh_s[4 + q]);
      const float n = tanhf(xn + bih_s[8 + q] + r * (hn + bhh_s[8 + q]));
      const float hprev = hbase[(size_t)b * 512 + c0 + q];
      const float hnew = (1.0f - z) * n + z * hprev;
      hout[(size_t)b * 512 + c0 + q] = hnew;
      sseq[((size_t)t * 256 + b) * 512 + c0 + q] = hnew;
    }
    bar_arrive(cg);
  }
}

// ---- attention: logits + softmax over L per batch row ----
__global__ __launch_bounds__(256) void attn_kernel(float* __restrict__ ws) {
  __shared__ float vt_s[512];
  __shared__ float lg[256];
  __shared__ float red[16];
  const int b = blockIdx.x, tid = threadIdx.x;
  const float* const vt = ws + VT_OFF + (size_t)b * 512;
  for (int i = tid; i < 512; i += 256) vt_s[i] = vt[i];
  __syncthreads();
  const int wv = tid >> 6, lane = tid & 63;
  const float* const sseq = ws + SSEQ_OFF;
  for (int l = wv; l < NL; l += 4) {
    const float* const sr = sseq + ((size_t)l * 256 + b) * 512;
    const float4 a  = *(const float4*)(sr + lane * 8);
    const float4 a2 = *(const float4*)(sr + lane * 8 + 4);
    float s = a.x * vt_s[lane * 8 + 0] + a.y * vt_s[lane * 8 + 1] +
              a.z * vt_s[lane * 8 + 2] + a.w * vt_s[lane * 8 + 3] +
              a2.x * vt_s[lane * 8 + 4] + a2.y * vt_s[lane * 8 + 5] +
              a2.z * vt_s[lane * 8 + 6] + a2.w * vt_s[lane * 8 + 7];
    for (int off = 32; off > 0; off >>= 1) s += __shfl_xor(s, off);
    if (lane == 0) lg[l] = s;
  }
  __syncthreads();
  float v = (tid < NL) ? lg[tid] : -3.0e38f;
  for (int off = 32; off > 0; off >>= 1) v = fmaxf(v, __shfl_xor(v, off));
  if ((tid & 63) == 0) red[tid >> 6] = v;
  __syncthreads();
  if (tid == 0) red[8] = fmaxf(fmaxf(red[0], red[1]), fmaxf(red[2], red[3]));
  __syncthreads();
  const float mx = red[8];
  const float e = (tid < NL) ? expf(lg[tid] - mx) : 0.0f;
  float se = e;
  for (int off = 32; off > 0; off >>= 1) se += __shfl_xor(se, off);
  if ((tid & 63) == 0) red[tid >> 6] = se;
  __syncthreads();
  if (tid == 0) red[9] = red[0] + red[1] + red[2] + red[3];
  __syncthreads();
  if (tid < NL) ws[ATT_OFF + (size_t)b * 200 + tid] = e / red[9];
}

// ---- persistent AUGRU: 2 phases per step (r,u then hhat), 200 steps ----
__global__ __launch_bounds__(256) void augru_kernel(const float* __restrict__ rw,
                                                    const float* __restrict__ rbias,
                                                    const float* __restrict__ uw,
                                                    const float* __restrict__ ubias,
                                                    const float* __restrict__ hw,
                                                    const float* __restrict__ hbias,
                                                    float* __restrict__ ws,
                                                    float* __restrict__ out) {
  __shared__ float wr_s[4 * 1024];
  __shared__ float wu_s[4 * 1024];
  __shared__ float wh_s[4 * 1024];
  __shared__ float rbs[4], ubs[4], hbs[4];

  const int bg = blockIdx.x >> 7, ng = blockIdx.x & 127;
  const int b0 = bg << 7, c0 = ng << 2;
  const int tid = threadIdx.x;
  for (int i = tid; i < 4 * 1024; i += 256) {
    const int q = i >> 10, kk = i & 1023;
    wr_s[i] = rw[(size_t)(c0 + q) * 1024 + kk];
    wu_s[i] = uw[(size_t)(c0 + q) * 1024 + kk];
    wh_s[i] = hw[(size_t)(c0 + q) * 1024 + kk];
  }
  if (tid < 4) {
    rbs[tid] = rbias[c0 + tid];
    ubs[tid] = ubias[c0 + tid];
    hbs[tid] = hbias[c0 + tid];
  }
  __syncthreads();

  float* const hbuf = ws + HBUF_OFF;
  float* const sseq = ws + SSEQ_OFF;
  float* const hrg = ws + HR_OFF;
  const float* const att = ws + ATT_OFF;
  unsigned long long* const bar = (unsigned long long*)(ws + BAR_OFF);
  unsigned long long* const c1 = bar + 32 + (bg << 4);
  unsigned long long* const c2 = bar + 64 + (bg << 4);

  const int bb = tid & 63, q = tid >> 6;  // 2 rows x 1 col per thread
  const int rA = b0 + bb, rB = rA + 64;
  const float* const wrq = wr_s + (q << 10);
  const float* const wuq = wu_s + (q << 10);
  const float* const whq = wh_s + (q << 10);

  for (int t = 0; t < NL; ++t) {
    const float* const xA = sseq + ((size_t)t * 256 + rA) * 512;
    const float* const xB = sseq + ((size_t)t * 256 + rB) * 512;
    // phase1 x-halves (independent of h) before the wait
    float prA = 0, puA = 0, prB = 0, puB = 0;
#pragma unroll 4
    for (int k = 0; k < 512; k += 4) {
      const float4 va = *(const float4*)(xA + k);
      const float4 vb = *(const float4*)(xB + k);
      const float4 w4r = *(const float4*)(wrq + 512 + k);
      const float4 w4u = *(const float4*)(wuq + 512 + k);
      prA += dot4(va, w4r); puA += dot4(va, w4u);
      prB += dot4(vb, w4r); puB += dot4(vb, w4u);
    }
    if (t > 0) bar_wait(c2, 128ull * (unsigned long long)t);
    const float* const hbase = hbuf + (size_t)(t & 1) * 131072;
    const float* const hA = hbase + (size_t)rA * 512;
    const float* const hB = hbase + (size_t)rB * 512;
#pragma unroll 4
    for (int k = 0; k < 512; k += 4) {
      const float4 va = *(const float4*)(hA + k);
      const float4 vb = *(const float4*)(hB + k);
      const float4 w4r = *(const float4*)(wrq + k);
      const float4 w4u = *(const float4*)(wuq + k);
      prA += dot4(va, w4r); puA += dot4(va, w4u);
      prB += dot4(vb, w4r); puB += dot4(vb, w4u);
    }
    const float rgA = sigmoidf_(prA + rbs[q]);
    const float rgB = sigmoidf_(prB + rbs[q]);
    const float ugA = sigmoidf_(puA + ubs[q]);  // kept in registers for phase2
    const float ugB = sigmoidf_(puB + ubs[q]);
    hrg[(size_t)rA * 512 + c0 + q] = rgA * hA[c0 + q];
    hrg[(size_t)rB * 512 + c0 + q] = rgB * hB[c0 + q];
    bar_arrive(c1);

    // phase2 x-halves before the wait on r*h
    float phA = 0, phB = 0;
#pragma unroll 4
    for (int k = 0; k < 512; k += 4) {
      const float4 va = *(const float4*)(xA + k);
      const float4 vb = *(const float4*)(xB + k);
      const float4 w4h = *(const float4*)(whq + 512 + k);
      phA += dot4(va, w4h); phB += dot4(vb, w4h);
    }
    bar_wait(c1, 128ull * (unsigned long long)(t + 1));
    const float* const hrA = hrg + (size_t)rA * 512;
    const float* const hrB = hrg + (size_t)rB * 512;
#pragma unroll 4
    for (int k = 0; k < 512; k += 4) {
      const float4 va = *(const float4*)(hrA + k);
      const float4 vb = *(const float4*)(hrB + k);
      const float4 w4h = *(const float4*)(whq + k);
      phA += dot4(va, w4h); phB += dot4(vb, w4h);
    }
    const float hhA = tanhf(phA + hbs[q]);
    const float hhB = tanhf(phB + hbs[q]);
    const float uA = att[(size_t)rA * 200 + t] * ugA;
    const float uB = att[(size_t)rB * 200 + t] * ugB;
    const float hpA = hbase[(size_t)rA * 512 + c0 + q];
    const float hpB = hbase[(size_t)rB * 512 + c0 + q];
    const float hnA = (1.0f - uA) * hpA + uA * hhA;
    const float hnB = (1.0f - uB) * hpB + uB * hhB;
    if (t == NL - 1) {
      out[(size_t)rA * 512 + c0 + q] = hnA;
      out[(size_t)rB * 512 + c0 + q] = hnB;
    } else {
      float* const hout = hbuf + (size_t)((t + 1) & 1) * 131072;
      hout[(size_t)rA * 512 + c0 + q] = hnA;
      hout[(size_t)rB * 512 + c0 + q] = hnB;
    }
    bar_arrive(c2);
  }
}

extern "C" void kernel_launch(void* const* d_in, const int* in_sizes, int n_in,
                              void* d_out, int out_size, void* d_ws, size_t ws_size,
                              hipStream_t stream) {
  (void)in_sizes; (void)n_in; (void)out_size; (void)ws_size;
  const float* session = (const float*)d_in[0];
  const float* target  = (const float*)d_in[1];
  const float* w       = (const float*)d_in[2];
  const float* wih     = (const float*)d_in[3];
  const float* whh     = (const float*)d_in[4];
  const float* bih     = (const float*)d_in[5];
  const float* bhh     = (const float*)d_in[6];
  const float* rw      = (const float*)d_in[7];
  const float* rb      = (const float*)d_in[8];
  const float* uw      = (const float*)d_in[9];
  const float* ub      = (const float*)d_in[10];
  const float* hw      = (const float*)d_in[11];
  const float* hb      = (const float*)d_in[12];
  float* ws  = (float*)d_ws;
  float* out = (float*)d_out;

  hipLaunchKernelGGL(init_kernel, dim3(64), dim3(256), 0, stream, ws);
  hipLaunchKernelGGL(vt_kernel, dim3(256), dim3(256), 0, stream, w, target, ws);
  hipLaunchKernelGGL(gru_kernel, dim3(256), dim3(256), 0, stream,
                     session, wih, whh, bih, bhh, ws);
  hipLaunchKernelGGL(attn_kernel, dim3(256), dim3(256), 0, stream, ws);
  hipLaunchKernelGGL(augru_kernel, dim3(256), dim3(256), 0, stream,
                     rw, rb, uw, ub, hw, hb, ws, out);
}